// Round 7
// baseline (2029.580 us; speedup 1.0000x reference)
//
#include <hip/hip_runtime.h>

#define NEQ_   4096
#define XDIM_  6144
#define EEDGES 32768
#define MAGIC  0x1234ABCD

typedef __bf16 bf16x8 __attribute__((ext_vector_type(8)));
typedef float  f32x4  __attribute__((ext_vector_type(4)));

__device__ __forceinline__ unsigned short f2bf(float f) {
    union { float f; unsigned u; } v; v.f = f;
    unsigned r = v.u + 0x7FFFu + ((v.u >> 16) & 1u);   // RNE
    return (unsigned short)(r >> 16);
}

// pack two relu'd floats to bf16 pair (round-half-up; inputs >= 0 post-relu)
__device__ __forceinline__ unsigned pk2(float x, float y) {
    x = fmaxf(x, 0.f); y = fmaxf(y, 0.f);
    union { float f; unsigned u; } ax, ay; ax.f = x; ay.f = y;
    return ((ax.u + 0x8000u) >> 16) | ((ay.u + 0x8000u) & 0xFFFF0000u);
}

__device__ __forceinline__ void gll16(const void* g, void* l) {
    __builtin_amdgcn_global_load_lds(
        (const __attribute__((address_space(1))) unsigned int*)g,
        (__attribute__((address_space(3))) unsigned int*)l, 16, 0, 0);
}

// ---- fused prep: block 0 = GCN (LDS-resident); blocks 1.. = tcvt; all = build_z ----
// 2048 blocks x 256 threads. Flag handshake: ws is poisoned 0xAA, so MAGIC != initial.
__global__ __launch_bounds__(256)
void prep(const float* __restrict__ x, const int* __restrict__ ei,
          const float* __restrict__ gw, const float* __restrict__ gb,
          const float* __restrict__ W1, const float* __restrict__ W2,
          const float* __restrict__ W3,
          unsigned short* __restrict__ W1t, unsigned short* __restrict__ W2t,
          unsigned short* __restrict__ W3t,
          float* __restrict__ gval, float* __restrict__ degv,
          unsigned short* __restrict__ z, int* __restrict__ flag)
{
    __shared__ union { int i[NEQ_]; float f[NEQ_]; } cd;   // counts, then dinv
    __shared__ float Sl[NEQ_];
    const int bid = blockIdx.x, tid = threadIdx.x;
    const int nb = gridDim.x;                 // 2048
    const int* src = ei;
    const int* dst = ei + EEDGES;

    if (bid == 0) {
        // GCN pipeline entirely in LDS (only nodes < 4096 are touched by edges)
        for (int i = tid; i < NEQ_; i += 256) { cd.i[i] = 0; Sl[i] = 0.f; }
        __syncthreads();
        for (int e = tid; e < EEDGES; e += 256) atomicAdd(&cd.i[dst[e]], 1);
        __syncthreads();
        for (int i = tid; i < NEQ_; i += 256) {
            float deg = 512.f * (float)cd.i[i] + 1.f;
            degv[i] = deg;                    // exact deg to global
            cd.f[i] = rsqrtf(deg);            // overwrite own slot: no cross-thread hazard
        }
        __syncthreads();
        for (int e = tid; e < EEDGES; e += 256) {
            int s = src[e], d = dst[e];
            float xf = x[(size_t)(s & 511) * XDIM_ + (s >> 9)];
            atomicAdd(&Sl[d], cd.f[s] * xf);
        }
        __syncthreads();
        for (int i = tid; i < NEQ_; i += 256)
            gval[i] = 512.f * cd.f[i] * Sl[i];
        __syncthreads();
        if (tid == 0) {
            __threadfence();
            __hip_atomic_store(flag, MAGIC, __ATOMIC_RELEASE, __HIP_MEMORY_SCOPE_AGENT);
        }
    } else {
        // tcvt: W[K][N] f32 -> Wt[N][K] bf16, 16n x 128k virtual tiles (r3/r6-validated body)
        const int lane = tid & 63, wave = tid >> 6;
        const int totvb = 6144 + 2048 + 4096;
        for (int vb = bid - 1; vb < totvb; vb += nb - 1) {
            const float* W; unsigned short* Wt; int K, N, bx, by;
            if (vb < 6144)      { W = W1; Wt = W1t; K = 6144; N = 2048; bx = vb & 127; by = vb >> 7; }
            else if (vb < 8192) { int l = vb - 6144; W = W2; Wt = W2t; K = 2048; N = 2048; bx = l & 127; by = l >> 7; }
            else                { int l = vb - 8192; W = W3; Wt = W3t; K = 2048; N = 4096; bx = l & 255; by = l >> 8; }
            int n  = bx * 16 + (lane >> 2);
            int kb = (by * 4 + wave) * 32 + (lane & 3) * 8;
            union { unsigned short h[8]; uint4 u; } cv;
            #pragma unroll
            for (int j = 0; j < 8; ++j) cv.h[j] = f2bf(W[(size_t)(kb + j) * N + n]);
            *(uint4*)(Wt + (size_t)n * K + kb) = cv.u;
        }
    }

    // build_z: needs gval/degv from block 0 — acquire-spin (flag set long before)
    if (bid != 0) {
        if (tid == 0) {
            while (__hip_atomic_load(flag, __ATOMIC_ACQUIRE, __HIP_MEMORY_SCOPE_AGENT) != MAGIC)
                __builtin_amdgcn_s_sleep(8);
        }
        __syncthreads();
    }
    {
        float w00 = gw[0], b0 = gb[0];
        const int totvb = 512 * 24;          // b x 256-wide column blocks
        for (int vb = bid; vb < totvb; vb += nb) {
            int b = vb / 24, cb = vb - b * 24;
            int i = cb * 256 + tid;
            float xv = x[(size_t)b * XDIM_ + i];
            float v;
            if (i >= NEQ_) {
                v = xv;
            } else if (i >= 8) {
                v = fmaxf(w00 * xv + b0, 0.f);
            } else {
                int n = i * 512 + b;
                v = fmaxf(w00 * (gval[n] + xv / degv[n]) + b0, 0.f);
            }
            z[(size_t)b * XDIM_ + i] = f2bf(v);
        }
    }
}

// ---- 64x64-tile MFMA GEMM (r6-validated), BK=64, 4 waves of 32x32 ----
// AMODE 0: A = bf16 [M][K] via global_load_lds.
// AMODE 1: A = relu(Pa[0]+Pa[1]+biasPrev) computed in-register during staging.
// OMODE 0: f32 partial to Pout[blockIdx.z][M][N]. OMODE 1: Cout = acc + biasOut.
template<int AMODE, int OMODE>
__global__ __launch_bounds__(256)
void gemm_f(const unsigned short* __restrict__ A,
            const float* __restrict__ Pa, const float* __restrict__ biasPrev,
            const unsigned short* __restrict__ Bt,
            float* __restrict__ Pout,
            float* __restrict__ Cout, const float* __restrict__ biasOut,
            int M, int N, int K, int kChunk)
{
    __shared__ unsigned short As[2 * 64 * 32];   // 8 KB  [kh][row][32]
    __shared__ unsigned short Bs[2 * 64 * 32];   // 8 KB
    const int tid = threadIdx.x, lane = tid & 63, wave = tid >> 6;
    const int m0 = blockIdx.x * 64, n0 = blockIdx.y * 64;
    const int wm = (wave >> 1) * 32, wn = (wave & 1) * 32;
    const int fr = lane & 15, fko = (lane >> 4) * 8;
    const int k0 = blockIdx.z * kChunk, k1 = k0 + kChunk;

    const int srow = tid >> 2;
    const int sko  = (tid & 3) * 8;
    const size_t boff = (size_t)(n0 + srow) * K + sko;
    unsigned short* bsl0 = &Bs[srow * 32 + sko];
    unsigned short* bsl1 = &Bs[2048 + srow * 32 + sko];

    const size_t aoff = (size_t)(m0 + srow) * K + sko;
    unsigned short* asl0 = &As[srow * 32 + sko];
    unsigned short* asl1 = &As[2048 + srow * 32 + sko];
    const float* p0 = Pa + (size_t)(m0 + srow) * K + sko;
    const float* p1 = p0 + (size_t)M * K;

    f32x4 acc[2][2] = {};

    for (int kk = k0; kk < k1; kk += 64) {
        gll16(Bt + boff + kk,      bsl0);
        gll16(Bt + boff + kk + 32, bsl1);
        if (AMODE == 0) {
            gll16(A + aoff + kk,      asl0);
            gll16(A + aoff + kk + 32, asl1);
        } else {
            #pragma unroll
            for (int kh = 0; kh < 2; ++kh) {
                int off = kk + kh * 32;
                f32x4 q0 = *(const f32x4*)(p0 + off);
                f32x4 q1 = *(const f32x4*)(p0 + off + 4);
                f32x4 r0 = *(const f32x4*)(p1 + off);
                f32x4 r1 = *(const f32x4*)(p1 + off + 4);
                f32x4 c0 = *(const f32x4*)(biasPrev + off + sko);
                f32x4 c1v = *(const f32x4*)(biasPrev + off + sko + 4);
                q0 += r0 + c0;
                q1 += r1 + c1v;
                uint4 w;
                w.x = pk2(q0[0], q0[1]);
                w.y = pk2(q0[2], q0[3]);
                w.z = pk2(q1[0], q1[1]);
                w.w = pk2(q1[2], q1[3]);
                *(uint4*)(&As[kh * 2048 + srow * 32 + sko]) = w;
            }
        }
        __syncthreads();

        bf16x8 af[2][2], bf[2][2];
        #pragma unroll
        for (int kh = 0; kh < 2; ++kh)
            #pragma unroll
            for (int t = 0; t < 2; ++t) {
                af[t][kh] = *(const bf16x8*)(&As[kh * 2048 + (wm + t * 16 + fr) * 32 + fko]);
                bf[t][kh] = *(const bf16x8*)(&Bs[kh * 2048 + (wn + t * 16 + fr) * 32 + fko]);
            }
        #pragma unroll
        for (int kh = 0; kh < 2; ++kh)
            #pragma unroll
            for (int mt = 0; mt < 2; ++mt)
                #pragma unroll
                for (int nt = 0; nt < 2; ++nt)
                    acc[mt][nt] = __builtin_amdgcn_mfma_f32_16x16x32_bf16(
                        af[mt][kh], bf[nt][kh], acc[mt][nt], 0, 0, 0);

        __syncthreads();
    }

    const int col = lane & 15, qr = (lane >> 4) * 4;
    if (OMODE == 0) {
        float* Pp = Pout + (size_t)blockIdx.z * M * N;
        #pragma unroll
        for (int mt = 0; mt < 2; ++mt)
        #pragma unroll
        for (int nt = 0; nt < 2; ++nt) {
            int gm = m0 + wm + mt * 16 + qr;
            int gn = n0 + wn + nt * 16 + col;
            #pragma unroll
            for (int r = 0; r < 4; ++r)
                Pp[(size_t)(gm + r) * N + gn] = acc[mt][nt][r];
        }
    } else {
        #pragma unroll
        for (int mt = 0; mt < 2; ++mt)
        #pragma unroll
        for (int nt = 0; nt < 2; ++nt) {
            int gm = m0 + wm + mt * 16 + qr;
            int gn = n0 + wn + nt * 16 + col;
            float bv = biasOut[gn];
            #pragma unroll
            for (int r = 0; r < 4; ++r)
                Cout[(size_t)(gm + r) * N + gn] = acc[mt][nt][r] + bv;
        }
    }
}

extern "C" void kernel_launch(void* const* d_in, const int* in_sizes, int n_in,
                              void* d_out, int out_size, void* d_ws, size_t ws_size,
                              hipStream_t stream)
{
    const float* x  = (const float*)d_in[0];
    const int*   ei = (const int*)d_in[1];
    const float* gw = (const float*)d_in[2];
    const float* gb = (const float*)d_in[3];
    const float* W1 = (const float*)d_in[4];
    const float* b1 = (const float*)d_in[5];
    const float* W2 = (const float*)d_in[6];
    const float* b2 = (const float*)d_in[7];
    const float* W3 = (const float*)d_in[8];
    const float* b3 = (const float*)d_in[9];
    float* out = (float*)d_out;

    char* ws = (char*)d_ws;
    unsigned short* z   = (unsigned short*)(ws);               //  6,291,456 B
    unsigned short* W1t = (unsigned short*)(ws + 6291456);     // 25,165,824 B
    unsigned short* W2t = (unsigned short*)(ws + 31457280);    //  8,388,608 B
    unsigned short* W3t = (unsigned short*)(ws + 39845888);    // 16,777,216 B
    float* Pa           = (float*)        (ws + 56623104);     //  8,388,608 B  [2][512][2048]
    float* Pb           = (float*)        (ws + 65011712);     //  8,388,608 B
    float* gval         = (float*)        (ws + 73400320);     // 16 KB
    float* degv         = (float*)        (ws + 73416704);     // 16 KB
    int*   flag         = (int*)          (ws + 73433088);     // 4 B (poisoned != MAGIC)

    // 1 launch: GCN (block 0, LDS) + weight transposes (blocks 1..) + build_z (all)
    hipLaunchKernelGGL(prep, dim3(2048), dim3(256), 0, stream,
                       x, ei, gw, gb, W1, W2, W3, W1t, W2t, W3t, gval, degv, z, flag);

    // L1: z[512,6144] @ W1t -> Pa (f32, S=2). 512 blocks, 48 iters
    hipLaunchKernelGGL((gemm_f<0, 0>), dim3(8, 32, 2), dim3(256), 0, stream,
                       z, nullptr, nullptr, W1t, Pa, nullptr, nullptr, 512, 2048, 6144, 3072);

    // L2: relu(Pa0+Pa1+b1) @ W2t -> Pb (f32, S=2). 512 blocks, 16 iters; reduce fused in A-staging
    hipLaunchKernelGGL((gemm_f<1, 0>), dim3(8, 32, 2), dim3(256), 0, stream,
                       nullptr, Pa, b1, W2t, Pb, nullptr, nullptr, 512, 2048, 2048, 1024);

    // L3: relu(Pb0+Pb1+b2) @ W3t + b3 -> out (f32). 512 blocks, 32 iters
    hipLaunchKernelGGL((gemm_f<1, 1>), dim3(8, 64, 1), dim3(256), 0, stream,
                       nullptr, Pb, b2, W3t, nullptr, out, b3, 512, 4096, 2048, 2048);
}

// Round 8
// 336.906 us; speedup vs baseline: 6.0242x; 6.0242x over previous
//
#include <hip/hip_runtime.h>

#define NEQ_   4096
#define XDIM_  6144
#define EEDGES 32768

typedef __bf16 bf16x8 __attribute__((ext_vector_type(8)));
typedef float  f32x4  __attribute__((ext_vector_type(4)));

__device__ __forceinline__ unsigned short f2bf(float f) {
    union { float f; unsigned u; } v; v.f = f;
    unsigned r = v.u + 0x7FFFu + ((v.u >> 16) & 1u);   // RNE
    return (unsigned short)(r >> 16);
}

// pack two relu'd floats to bf16 pair (round-half-up; inputs >= 0 post-relu)
__device__ __forceinline__ unsigned pk2(float x, float y) {
    x = fmaxf(x, 0.f); y = fmaxf(y, 0.f);
    union { float f; unsigned u; } ax, ay; ax.f = x; ay.f = y;
    return ((ax.u + 0x8000u) >> 16) | ((ay.u + 0x8000u) & 0xFFFF0000u);
}

__device__ __forceinline__ void gll16(const void* g, void* l) {
    __builtin_amdgcn_global_load_lds(
        (const __attribute__((address_space(1))) unsigned int*)g,
        (__attribute__((address_space(3))) unsigned int*)l, 16, 0, 0);
}

// ---- GCN, one block, LDS-resident (only nodes < 4096 are touched by edges) ----
__global__ __launch_bounds__(1024)
void gcn_one(const float* __restrict__ x, const int* __restrict__ ei,
             float* __restrict__ gval, float* __restrict__ degv)
{
    __shared__ union { int i[NEQ_]; float f[NEQ_]; } cd;   // counts -> dinv
    __shared__ float Sl[NEQ_];
    const int tid = threadIdx.x;
    const int* src = ei;
    const int* dst = ei + EEDGES;

    for (int i = tid; i < NEQ_; i += 1024) { cd.i[i] = 0; Sl[i] = 0.f; }
    __syncthreads();
    for (int e = tid; e < EEDGES; e += 1024) atomicAdd(&cd.i[dst[e]], 1);
    __syncthreads();
    for (int i = tid; i < NEQ_; i += 1024) {
        float deg = 512.f * (float)cd.i[i] + 1.f;
        degv[i] = deg;
        cd.f[i] = rsqrtf(deg);     // overwrite own slot — no cross-thread hazard
    }
    __syncthreads();
    #pragma unroll 4
    for (int e = tid; e < EEDGES; e += 1024) {
        int s = src[e], d = dst[e];
        float xf = x[(size_t)(s & 511) * XDIM_ + (s >> 9)];
        atomicAdd(&Sl[d], cd.f[s] * xf);
    }
    __syncthreads();
    for (int i = tid; i < NEQ_; i += 1024)
        gval[i] = 512.f * cd.f[i] * Sl[i];
}

// ---- prep: build_z + weight transpose/convert, full grid, no LDS, no sync ----
__global__ __launch_bounds__(256)
void prep(const float* __restrict__ x,
          const float* __restrict__ gw, const float* __restrict__ gb,
          const float* __restrict__ W1, const float* __restrict__ W2,
          const float* __restrict__ W3,
          unsigned short* __restrict__ W1t, unsigned short* __restrict__ W2t,
          unsigned short* __restrict__ W3t,
          const float* __restrict__ gval, const float* __restrict__ degv,
          unsigned short* __restrict__ z)
{
    const int bid = blockIdx.x, tid = threadIdx.x;
    const int nb = gridDim.x;                 // 2048

    // build_z: 512 rows x 24 column-blocks of 256
    {
        float w00 = gw[0], b0 = gb[0];
        for (int vb = bid; vb < 512 * 24; vb += nb) {
            int b = vb / 24, cb = vb - b * 24;
            int i = cb * 256 + tid;
            float xv = x[(size_t)b * XDIM_ + i];
            float v;
            if (i >= NEQ_) {
                v = xv;
            } else if (i >= 8) {
                v = fmaxf(w00 * xv + b0, 0.f);
            } else {
                int n = i * 512 + b;
                v = fmaxf(w00 * (gval[n] + xv / degv[n]) + b0, 0.f);
            }
            z[(size_t)b * XDIM_ + i] = f2bf(v);
        }
    }

    // tcvt: W[K][N] f32 -> Wt[N][K] bf16, 16n x 128k virtual tiles (r3/r6-validated)
    {
        const int lane = tid & 63, wave = tid >> 6;
        const int totvb = 6144 + 2048 + 4096;
        for (int vb = bid; vb < totvb; vb += nb) {
            const float* W; unsigned short* Wt; int K, N, bx, by;
            if (vb < 6144)      { W = W1; Wt = W1t; K = 6144; N = 2048; bx = vb & 127; by = vb >> 7; }
            else if (vb < 8192) { int l = vb - 6144; W = W2; Wt = W2t; K = 2048; N = 2048; bx = l & 127; by = l >> 7; }
            else                { int l = vb - 8192; W = W3; Wt = W3t; K = 2048; N = 4096; bx = l & 255; by = l >> 8; }
            int n  = bx * 16 + (lane >> 2);
            int kb = (by * 4 + wave) * 32 + (lane & 3) * 8;
            union { unsigned short h[8]; uint4 u; } cv;
            #pragma unroll
            for (int j = 0; j < 8; ++j) cv.h[j] = f2bf(W[(size_t)(kb + j) * N + n]);
            *(uint4*)(Wt + (size_t)n * K + kb) = cv.u;
        }
    }
}

// ---- 64x64-tile MFMA GEMM (r6-validated), BK=64, 4 waves of 32x32 ----
// AMODE 0: A = bf16 [M][K] via global_load_lds.
// AMODE 1: A = relu(Pa[0]+Pa[1]+biasPrev) computed in-register during staging.
// OMODE 0: f32 partial to Pout[blockIdx.z][M][N]. OMODE 1: Cout = acc + biasOut.
template<int AMODE, int OMODE>
__global__ __launch_bounds__(256)
void gemm_f(const unsigned short* __restrict__ A,
            const float* __restrict__ Pa, const float* __restrict__ biasPrev,
            const unsigned short* __restrict__ Bt,
            float* __restrict__ Pout,
            float* __restrict__ Cout, const float* __restrict__ biasOut,
            int M, int N, int K, int kChunk)
{
    __shared__ unsigned short As[2 * 64 * 32];   // 8 KB  [kh][row][32]
    __shared__ unsigned short Bs[2 * 64 * 32];   // 8 KB
    const int tid = threadIdx.x, lane = tid & 63, wave = tid >> 6;
    const int m0 = blockIdx.x * 64, n0 = blockIdx.y * 64;
    const int wm = (wave >> 1) * 32, wn = (wave & 1) * 32;
    const int fr = lane & 15, fko = (lane >> 4) * 8;
    const int k0 = blockIdx.z * kChunk, k1 = k0 + kChunk;

    const int srow = tid >> 2;
    const int sko  = (tid & 3) * 8;
    const size_t boff = (size_t)(n0 + srow) * K + sko;
    unsigned short* bsl0 = &Bs[srow * 32 + sko];
    unsigned short* bsl1 = &Bs[2048 + srow * 32 + sko];

    const size_t aoff = (size_t)(m0 + srow) * K + sko;
    unsigned short* asl0 = &As[srow * 32 + sko];
    unsigned short* asl1 = &As[2048 + srow * 32 + sko];
    const float* p0 = Pa + (size_t)(m0 + srow) * K + sko;
    const float* p1 = p0 + (size_t)M * K;

    f32x4 acc[2][2] = {};

    for (int kk = k0; kk < k1; kk += 64) {
        gll16(Bt + boff + kk,      bsl0);
        gll16(Bt + boff + kk + 32, bsl1);
        if (AMODE == 0) {
            gll16(A + aoff + kk,      asl0);
            gll16(A + aoff + kk + 32, asl1);
        } else {
            #pragma unroll
            for (int kh = 0; kh < 2; ++kh) {
                int off = kk + kh * 32;
                f32x4 q0 = *(const f32x4*)(p0 + off);
                f32x4 q1 = *(const f32x4*)(p0 + off + 4);
                f32x4 r0 = *(const f32x4*)(p1 + off);
                f32x4 r1 = *(const f32x4*)(p1 + off + 4);
                f32x4 c0 = *(const f32x4*)(biasPrev + off + sko);
                f32x4 c1v = *(const f32x4*)(biasPrev + off + sko + 4);
                q0 += r0 + c0;
                q1 += r1 + c1v;
                uint4 w;
                w.x = pk2(q0[0], q0[1]);
                w.y = pk2(q0[2], q0[3]);
                w.z = pk2(q1[0], q1[1]);
                w.w = pk2(q1[2], q1[3]);
                *(uint4*)(&As[kh * 2048 + srow * 32 + sko]) = w;
            }
        }
        __syncthreads();

        bf16x8 af[2][2], bf[2][2];
        #pragma unroll
        for (int kh = 0; kh < 2; ++kh)
            #pragma unroll
            for (int t = 0; t < 2; ++t) {
                af[t][kh] = *(const bf16x8*)(&As[kh * 2048 + (wm + t * 16 + fr) * 32 + fko]);
                bf[t][kh] = *(const bf16x8*)(&Bs[kh * 2048 + (wn + t * 16 + fr) * 32 + fko]);
            }
        #pragma unroll
        for (int kh = 0; kh < 2; ++kh)
            #pragma unroll
            for (int mt = 0; mt < 2; ++mt)
                #pragma unroll
                for (int nt = 0; nt < 2; ++nt)
                    acc[mt][nt] = __builtin_amdgcn_mfma_f32_16x16x32_bf16(
                        af[mt][kh], bf[nt][kh], acc[mt][nt], 0, 0, 0);

        __syncthreads();
    }

    const int col = lane & 15, qr = (lane >> 4) * 4;
    if (OMODE == 0) {
        float* Pp = Pout + (size_t)blockIdx.z * M * N;
        #pragma unroll
        for (int mt = 0; mt < 2; ++mt)
        #pragma unroll
        for (int nt = 0; nt < 2; ++nt) {
            int gm = m0 + wm + mt * 16 + qr;
            int gn = n0 + wn + nt * 16 + col;
            #pragma unroll
            for (int r = 0; r < 4; ++r)
                Pp[(size_t)(gm + r) * N + gn] = acc[mt][nt][r];
        }
    } else {
        #pragma unroll
        for (int mt = 0; mt < 2; ++mt)
        #pragma unroll
        for (int nt = 0; nt < 2; ++nt) {
            int gm = m0 + wm + mt * 16 + qr;
            int gn = n0 + wn + nt * 16 + col;
            float bv = biasOut[gn];
            #pragma unroll
            for (int r = 0; r < 4; ++r)
                Cout[(size_t)(gm + r) * N + gn] = acc[mt][nt][r] + bv;
        }
    }
}

extern "C" void kernel_launch(void* const* d_in, const int* in_sizes, int n_in,
                              void* d_out, int out_size, void* d_ws, size_t ws_size,
                              hipStream_t stream)
{
    const float* x  = (const float*)d_in[0];
    const int*   ei = (const int*)d_in[1];
    const float* gw = (const float*)d_in[2];
    const float* gb = (const float*)d_in[3];
    const float* W1 = (const float*)d_in[4];
    const float* b1 = (const float*)d_in[5];
    const float* W2 = (const float*)d_in[6];
    const float* b2 = (const float*)d_in[7];
    const float* W3 = (const float*)d_in[8];
    const float* b3 = (const float*)d_in[9];
    float* out = (float*)d_out;

    char* ws = (char*)d_ws;
    unsigned short* z   = (unsigned short*)(ws);               //  6,291,456 B
    unsigned short* W1t = (unsigned short*)(ws + 6291456);     // 25,165,824 B
    unsigned short* W2t = (unsigned short*)(ws + 31457280);    //  8,388,608 B
    unsigned short* W3t = (unsigned short*)(ws + 39845888);    // 16,777,216 B
    float* Pa           = (float*)        (ws + 56623104);     //  8,388,608 B  [2][512][2048]
    float* Pb           = (float*)        (ws + 65011712);     //  8,388,608 B
    float* gval         = (float*)        (ws + 73400320);     // 16 KB
    float* degv         = (float*)        (ws + 73416704);     // 16 KB

    // 1: GCN in one block's LDS
    hipLaunchKernelGGL(gcn_one, dim3(1), dim3(1024), 0, stream, x, ei, gval, degv);

    // 2: build_z + all weight transposes, full grid, no internal sync
    hipLaunchKernelGGL(prep, dim3(2048), dim3(256), 0, stream,
                       x, gw, gb, W1, W2, W3, W1t, W2t, W3t, gval, degv, z);

    // 3: L1: z[512,6144] @ W1t -> Pa (f32, S=2). 512 blocks, 48 iters
    hipLaunchKernelGGL((gemm_f<0, 0>), dim3(8, 32, 2), dim3(256), 0, stream,
                       z, nullptr, nullptr, W1t, Pa, nullptr, nullptr, 512, 2048, 6144, 3072);

    // 4: L2: relu(Pa0+Pa1+b1) @ W2t -> Pb (f32, S=2). 512 blocks, 16 iters
    hipLaunchKernelGGL((gemm_f<1, 0>), dim3(8, 32, 2), dim3(256), 0, stream,
                       nullptr, Pa, b1, W2t, Pb, nullptr, nullptr, 512, 2048, 2048, 1024);

    // 5: L3: relu(Pb0+Pb1+b2) @ W3t + b3 -> out (f32). 512 blocks, 32 iters
    hipLaunchKernelGGL((gemm_f<1, 1>), dim3(8, 64, 1), dim3(256), 0, stream,
                       nullptr, Pb, b2, W3t, nullptr, out, b3, 512, 4096, 2048, 2048);
}